// Round 9
// baseline (206.933 us; speedup 1.0000x reference)
//
#include <hip/hip_runtime.h>

#define H 16
#define NSEQ 2048
#define HD 64
#define CDIM 1024

typedef __attribute__((ext_vector_type(8))) short s8v;
typedef __attribute__((ext_vector_type(4))) float f4v;
typedef __attribute__((ext_vector_type(16))) float f16v;
typedef __attribute__((ext_vector_type(4))) unsigned u4v;

#define GLL(g, l) __builtin_amdgcn_global_load_lds( \
    (const __attribute__((address_space(1))) void*)(g), \
    (__attribute__((address_space(3))) void*)(l), 16, 0, 0)

__device__ __forceinline__ short f2bf(float f) {  // RNE-ish
  unsigned u = __float_as_uint(f);
  unsigned r = (u + 0x7fffu + ((u >> 16) & 1u)) >> 16;
  return (short)r;
}
__device__ __forceinline__ short f2bf_fast(float f) {
  return (short)((__float_as_uint(f) + 0x8000u) >> 16);
}
__device__ __forceinline__ unsigned pk(float a, float b) {  // (bf16(a) low, bf16(b) high)
  unsigned ua = __float_as_uint(a) + 0x8000u;
  unsigned ub = __float_as_uint(b) + 0x8000u;
  return __builtin_amdgcn_perm(ub, ua, 0x07060302);
}

// ---------------- fused fp32->bf16 (x, qkv_w, proj_w) + gate MLP ----------------
__global__ __launch_bounds__(256) void cvt_gate_kernel(
    const float* __restrict__ a, const float* __restrict__ b, const float* __restrict__ c,
    const float* __restrict__ mask,
    const float* __restrict__ g1w, const float* __restrict__ g1b,
    const float* __restrict__ g2w, const float* __restrict__ g2b,
    short* __restrict__ oa, short* __restrict__ ob, short* __restrict__ oc,
    float* __restrict__ gate) {
  int i = blockIdx.x * 256 + threadIdx.x;
  if (i >= 2097152) {  // last 16 blocks: gate MLP for 4096 (b,n)
    int j = i - 2097152;
    float m = mask[j];
    float acc = 0.f;
    for (int k = 0; k < 256; k++) {
      float h = fmaxf(m * g1w[k] + g1b[k], 0.f);
      acc += g2w[k] * h;
    }
    gate[j] = 1.f / (1.f + __expf(-(acc + g2b[0])));
    return;
  }
  const float* src; short* dst; int j;
  if (i < 1048576)      { src = a; dst = oa; j = i; }
  else if (i < 1835008) { src = b; dst = ob; j = i - 1048576; }
  else                  { src = c; dst = oc; j = i - 1835008; }
  float4 f = ((const float4*)src)[j];
  short4 s;
  s.x = f2bf(f.x); s.y = f2bf(f.y); s.z = f2bf(f.z); s.w = f2bf(f.w);
  ((short4*)dst)[j] = s;
}

// ---------------- QKV GEMM, swapped orientation: A=W (feat), B=X (token) ----------------
__global__ __launch_bounds__(256) void gemm_qkv(const short* __restrict__ X,
    const short* __restrict__ W, const float* __restrict__ bias, const float* __restrict__ gate,
    short* __restrict__ qws, short* __restrict__ kws, short* __restrict__ vtws) {
  __shared__ __align__(16) short Ft[8192];   // W tile, 2 bufs of 128x32
  __shared__ __align__(16) short Tt[8192];   // X tile, 2 bufs
  const int K = CDIM;
  int tid = threadIdx.x;
  int lane = tid & 63, w = tid >> 6;
  int quad = lane >> 4, l15 = lane & 15;
  int wm = w >> 1, wn = w & 1;
  long featBase = (long)blockIdx.x * 128;
  long tokBase  = (long)blockIdx.y * 128;
  const f4v fz = {0.f, 0.f, 0.f, 0.f};
  f4v acc[4][4];
#pragma unroll
  for (int i = 0; i < 4; i++)
#pragma unroll
    for (int j = 0; j < 4; j++) acc[i][j] = fz;

  int j0 = tid, j1 = 256 + tid;
  int sr0 = j0 >> 2, sp0 = j0 & 3, sc0 = sp0 ^ ((sr0 >> 1) & 3);
  int sr1 = j1 >> 2, sp1 = j1 & 3, sc1 = sp1 ^ ((sr1 >> 1) & 3);
  const short* Wa = W + (featBase + sr0) * K + sc0 * 8;
  const short* Wb = W + (featBase + sr1) * K + sc1 * 8;
  const short* Xa = X + (tokBase + sr0) * K + sc0 * 8;
  const short* Xb = X + (tokBase + sr1) * K + sc1 * 8;

  GLL(Wa, &Ft[j0 * 8]);
  GLL(Wb, &Ft[j1 * 8]);
  GLL(Xa, &Tt[j0 * 8]);
  GLL(Xb, &Tt[j1 * 8]);

  for (int it = 0; it < 32; it++) {
    int cur = (it & 1) * 4096;
    __syncthreads();
    s8v a[4], b[4];
#pragma unroll
    for (int mi = 0; mi < 4; mi++) {
      int row = wm * 64 + mi * 16 + l15;
      a[mi] = *(const s8v*)&Ft[cur + row * 32 + ((quad ^ ((row >> 1) & 3)) * 8)];
    }
#pragma unroll
    for (int ni = 0; ni < 4; ni++) {
      int row = wn * 64 + ni * 16 + l15;
      b[ni] = *(const s8v*)&Tt[cur + row * 32 + ((quad ^ ((row >> 1) & 3)) * 8)];
    }
    if (it < 31) {
      int nb = 4096 - cur;
      int k0 = (it + 1) * 32;
      GLL(Wa + k0, &Ft[nb + j0 * 8]);
      GLL(Wb + k0, &Ft[nb + j1 * 8]);
      GLL(Xa + k0, &Tt[nb + j0 * 8]);
      GLL(Xb + k0, &Tt[nb + j1 * 8]);
    }
#pragma unroll
    for (int mi = 0; mi < 4; mi++)
#pragma unroll
      for (int ni = 0; ni < 4; ni++)
        acc[mi][ni] = __builtin_amdgcn_mfma_f32_16x16x32_bf16(a[mi], b[ni], acc[mi][ni], 0, 0, 0);
  }
#pragma unroll
  for (int mi = 0; mi < 4; mi++) {
    int feat0 = (int)featBase + wm * 64 + mi * 16 + quad * 4;
    int which = feat0 >> 10, cc = feat0 & 1023;
    int hh = cc >> 6, dd = cc & 63;
    f4v b4 = *(const f4v*)&bias[feat0];
#pragma unroll
    for (int ni = 0; ni < 4; ni++) {
      int token = (int)tokBase + wn * 64 + ni * 16 + l15;
      int bb = token >> 11, nn = token & 2047;
      if (which == 0) {
        short4 pv;
        pv.x = f2bf((acc[mi][ni][0] + b4[0]) * 0.125f);
        pv.y = f2bf((acc[mi][ni][1] + b4[1]) * 0.125f);
        pv.z = f2bf((acc[mi][ni][2] + b4[2]) * 0.125f);
        pv.w = f2bf((acc[mi][ni][3] + b4[3]) * 0.125f);
        *(short4*)&qws[((bb * H + hh) * NSEQ + nn) * HD + dd] = pv;
      } else if (which == 1) {
        float gl = gate[token] * 1.44269504f;
        short4 pv;
        pv.x = f2bf((acc[mi][ni][0] + b4[0]) * gl);
        pv.y = f2bf((acc[mi][ni][1] + b4[1]) * gl);
        pv.z = f2bf((acc[mi][ni][2] + b4[2]) * gl);
        pv.w = f2bf((acc[mi][ni][3] + b4[3]) * gl);
        *(short4*)&kws[((bb * H + hh) * NSEQ + nn) * HD + dd] = pv;
      } else {
#pragma unroll
        for (int r = 0; r < 4; r++)
          vtws[((bb * H + hh) * HD + dd + r) * NSEQ + nn] = f2bf(acc[mi][ni][r] + b4[r]);
      }
    }
  }
}

// ---------------- Proj GEMM: 64x128 tile, dbuf single-barrier ----------------
__global__ __launch_bounds__(256) void gemm_proj(const short* __restrict__ X,
    const short* __restrict__ W, const float* __restrict__ bias, float* __restrict__ out) {
  __shared__ __align__(16) short At[4096];
  __shared__ __align__(16) short Bt[8192];
  const int K = CDIM;
  int tid = threadIdx.x;
  int lane = tid & 63, w = tid >> 6;
  int quad = lane >> 4, l15 = lane & 15;
  int wm = w >> 1, wn = w & 1;
  long rowBase = (long)blockIdx.y * 64;
  long colBase = (long)blockIdx.x * 128;
  const f4v fz = {0.f, 0.f, 0.f, 0.f};
  f4v acc[2][4];
#pragma unroll
  for (int i = 0; i < 2; i++)
#pragma unroll
    for (int j = 0; j < 4; j++) acc[i][j] = fz;

  int j0 = tid, j1 = 256 + tid;
  int sr0 = j0 >> 2, sp0 = j0 & 3, sc0 = sp0 ^ ((sr0 >> 1) & 3);
  int sr1 = j1 >> 2, sp1 = j1 & 3, sc1 = sp1 ^ ((sr1 >> 1) & 3);
  const short* Xa = X + (rowBase + sr0) * K + sc0 * 8;
  const short* Wa = W + (colBase + sr0) * K + sc0 * 8;
  const short* Wb = W + (colBase + sr1) * K + sc1 * 8;

  GLL(Xa, &At[j0 * 8]);
  GLL(Wa, &Bt[j0 * 8]);
  GLL(Wb, &Bt[j1 * 8]);

  for (int it = 0; it < 32; it++) {
    int curA = (it & 1) * 2048, curB = (it & 1) * 4096;
    __syncthreads();
    s8v a[2], b[4];
#pragma unroll
    for (int mi = 0; mi < 2; mi++) {
      int row = wm * 32 + mi * 16 + l15;
      a[mi] = *(const s8v*)&At[curA + row * 32 + ((quad ^ ((row >> 1) & 3)) * 8)];
    }
#pragma unroll
    for (int ni = 0; ni < 4; ni++) {
      int row = wn * 64 + ni * 16 + l15;
      b[ni] = *(const s8v*)&Bt[curB + row * 32 + ((quad ^ ((row >> 1) & 3)) * 8)];
    }
    if (it < 31) {
      int nbA = 2048 - curA, nbB = 4096 - curB;
      int k0 = (it + 1) * 32;
      GLL(Xa + k0, &At[nbA + j0 * 8]);
      GLL(Wa + k0, &Bt[nbB + j0 * 8]);
      GLL(Wb + k0, &Bt[nbB + j1 * 8]);
    }
#pragma unroll
    for (int mi = 0; mi < 2; mi++)
#pragma unroll
      for (int ni = 0; ni < 4; ni++)
        acc[mi][ni] = __builtin_amdgcn_mfma_f32_16x16x32_bf16(a[mi], b[ni], acc[mi][ni], 0, 0, 0);
  }
#pragma unroll
  for (int mi = 0; mi < 2; mi++) {
    int row = (int)rowBase + wm * 32 + mi * 16 + quad * 4;
#pragma unroll
    for (int ni = 0; ni < 4; ni++) {
      int col = (int)colBase + wn * 64 + ni * 16 + l15;
      float bcol = bias[col];
#pragma unroll
      for (int r = 0; r < 4; r++)
        out[(long)(row + r) * CDIM + col] = acc[mi][ni][r] + bcol;
    }
  }
}

// ---------------- Flash attention v9: q-row partition, NO cross-wave combine ----------------
// 256-thread blocks, 4 waves: wave wq owns q-rows qbase + wq*32 + l31, ALL keys.
// Per K-tile (BK=64): each wave does S^T over both 32-key halves (kt=0,1), exp2, register
// P-exchange, PV. Each wave's l is complete -> normalize + store directly, no epilogue LDS.
// grid 512 = (qt 16) x (bh 32 low bits, XCD L2 locality). dbuf GLL pipeline.
__global__ __launch_bounds__(256, 2) void attn_kernel(const short* __restrict__ qws,
    const short* __restrict__ kws, const short* __restrict__ vtws,
    short* __restrict__ attn_out) {
  __shared__ __align__(16) short KB[8192];   // [2][64][64]
  __shared__ __align__(16) short VB[8192];   // [2][64][64]

  int tid = threadIdx.x;
  int lane = tid & 63;
  int w = tid >> 6;                  // wave index = wq (q-row group)
  int l31 = lane & 31, hf = lane >> 5;
  int bh = blockIdx.x & 31, qt = blockIdx.x >> 5;
  int b = bh >> 4, head = bh & 15;
  int qbase = qt * 128;

  // Q B-frags: qf[ds] = B[n=qrow w*32+l31][k=d ds*16+hf*8+j]
  s8v qf[4];
  {
    const short* qp = qws + ((long)bh * NSEQ + qbase + w * 32 + l31) * HD + hf * 8;
#pragma unroll
    for (int ds = 0; ds < 4; ds++) qf[ds] = *(const s8v*)&qp[ds * 16];
  }

  const f16v fz16 = {0.f,0.f,0.f,0.f,0.f,0.f,0.f,0.f,0.f,0.f,0.f,0.f,0.f,0.f,0.f,0.f};
  f16v oacc[2] = {fz16, fz16};   // [nt] O^T: lane l31 = qrow; reg r -> d = nt*32+(r&3)+8*(r>>2)+4hf
  float l_r = 0.f;

  // staging: wave w stages rows w*16 + r8 and w*16+8+r8 of K and V tiles (2 GLLs each)
  int r8 = lane >> 3, c8 = lane & 7;
  int row0 = w * 16 + r8, row1 = row0 + 8;   // row&7 == r8 for both
  int sc = (c8 ^ r8) * 8;
  const short* kg0 = kws + ((long)bh * NSEQ + row0) * HD + sc;
  const short* kg1 = kws + ((long)bh * NSEQ + row1) * HD + sc;
  const short* vg0 = vtws + ((long)bh * HD + row0) * NSEQ + sc;
  const short* vg1 = vtws + ((long)bh * HD + row1) * NSEQ + sc;
  int lds0 = (w * 16) * 64 + lane * 8;       // uniform base + lane*16B

  // prologue: tile 0 -> buf 0
  GLL(kg0, KB + lds0);
  GLL(kg1, KB + lds0 + 512);
  GLL(vg0, VB + lds0);
  GLL(vg1, VB + lds0 + 512);

  for (int it = 0; it < 32; it++) {
    int cur = (it & 1) * 4096;
    __syncthreads();
    const short* Kc = KB + cur;
    const short* Vc = VB + cur;
    // frag reads (before GLL issue): K rows for both key halves; V chunks for all 4 key groups
    s8v ak[2][4];
#pragma unroll
    for (int kt = 0; kt < 2; kt++)
#pragma unroll
      for (int ds = 0; ds < 4; ds++)
        ak[kt][ds] = *(const s8v*)&Kc[(kt * 32 + l31) * 64 + (((2 * ds + hf) ^ (l31 & 7)) * 8)];
    s8v av[2][4];
#pragma unroll
    for (int nt = 0; nt < 2; nt++)
#pragma unroll
      for (int kg = 0; kg < 4; kg++)
        av[nt][kg] = *(const s8v*)&Vc[(nt * 32 + l31) * 64 + (((kg * 2 + hf) ^ (l31 & 7)) * 8)];
    // prefetch tile it+1 into other buffer
    if (it < 31) {
      int nb = 4096 - cur;
      long koff = (long)(it + 1) * 64 * HD;
      int voff = (it + 1) * 64;
      GLL(kg0 + koff, KB + nb + lds0);
      GLL(kg1 + koff, KB + nb + lds0 + 512);
      GLL(vg0 + voff, VB + nb + lds0);
      GLL(vg1 + voff, VB + nb + lds0 + 512);
    }
    // per key-half kt: S^T -> exp2 -> pack -> exchange -> PV (all registers, const indices)
#pragma unroll
    for (int kt = 0; kt < 2; kt++) {
      f16v s = fz16;
#pragma unroll
      for (int ds = 0; ds < 4; ds++)
        s = __builtin_amdgcn_mfma_f32_32x32x16_bf16(ak[kt][ds], qf[ds], s, 0, 0, 0);
      f16v pv;
#pragma unroll
      for (int i = 0; i < 16; i++) pv[i] = __builtin_amdgcn_exp2f(s[i]);
      float ls = 0.f;
#pragma unroll
      for (int i = 0; i < 16; i++) ls += pv[i];
      ls += __shfl_xor(ls, 32);
      l_r += ls;
      // pack: d{2g},d{2g+1} hold keys kt*32 + 8g+4hf+{0..3} for qrow l31
      unsigned d0 = pk(pv[0],  pv[1]),  d1 = pk(pv[2],  pv[3]);
      unsigned d2 = pk(pv[4],  pv[5]),  d3 = pk(pv[6],  pv[7]);
      unsigned d4 = pk(pv[8],  pv[9]),  d5 = pk(pv[10], pv[11]);
      unsigned d6 = pk(pv[12], pv[13]), d7 = pk(pv[14], pv[15]);
      // ks = 0 (keys kt*32 + 0..15)
      {
        unsigned send0 = hf ? d0 : d2, send1 = hf ? d1 : d3;
        unsigned own0  = hf ? d2 : d0, own1  = hf ? d3 : d1;
        unsigned recv0 = (unsigned)__shfl_xor((int)send0, 32);
        unsigned recv1 = (unsigned)__shfl_xor((int)send1, 32);
        u4v t;
        t.x = hf ? recv0 : own0;
        t.y = hf ? recv1 : own1;
        t.z = hf ? own0 : recv0;
        t.w = hf ? own1 : recv1;
        s8v bv = __builtin_bit_cast(s8v, t);
#pragma unroll
        for (int nt = 0; nt < 2; nt++)
          oacc[nt] = __builtin_amdgcn_mfma_f32_32x32x16_bf16(av[nt][kt * 2 + 0], bv, oacc[nt], 0, 0, 0);
      }
      // ks = 1 (keys kt*32 + 16..31)
      {
        unsigned send0 = hf ? d4 : d6, send1 = hf ? d5 : d7;
        unsigned own0  = hf ? d6 : d4, own1  = hf ? d7 : d5;
        unsigned recv0 = (unsigned)__shfl_xor((int)send0, 32);
        unsigned recv1 = (unsigned)__shfl_xor((int)send1, 32);
        u4v t;
        t.x = hf ? recv0 : own0;
        t.y = hf ? recv1 : own1;
        t.z = hf ? own0 : recv0;
        t.w = hf ? own1 : recv1;
        s8v bv = __builtin_bit_cast(s8v, t);
#pragma unroll
        for (int nt = 0; nt < 2; nt++)
          oacc[nt] = __builtin_amdgcn_mfma_f32_32x32x16_bf16(av[nt][kt * 2 + 1], bv, oacc[nt], 0, 0, 0);
      }
    }
  }

  // ---- direct store: each wave's l is complete; no LDS, no barrier, const indices ----
  float li = __builtin_amdgcn_rcpf(l_r);
  long outbase = ((long)b * NSEQ + qbase + w * 32 + l31) * CDIM + head * HD;
#pragma unroll
  for (int nt = 0; nt < 2; nt++)
#pragma unroll
    for (int g = 0; g < 4; g++) {
      short4 s4;
      s4.x = f2bf_fast(oacc[nt][4 * g]     * li);
      s4.y = f2bf_fast(oacc[nt][4 * g + 1] * li);
      s4.z = f2bf_fast(oacc[nt][4 * g + 2] * li);
      s4.w = f2bf_fast(oacc[nt][4 * g + 3] * li);
      *(short4*)&attn_out[outbase + nt * 32 + 8 * g + 4 * hf] = s4;
    }
}

extern "C" void kernel_launch(void* const* d_in, const int* in_sizes, int n_in,
                              void* d_out, int out_size, void* d_ws, size_t ws_size,
                              hipStream_t stream) {
  const float* x     = (const float*)d_in[0];
  const float* mask  = (const float*)d_in[1];
  const float* qkvw  = (const float*)d_in[2];
  const float* qkvb  = (const float*)d_in[3];
  const float* projw = (const float*)d_in[4];
  const float* projb = (const float*)d_in[5];
  const float* g1w   = (const float*)d_in[6];
  const float* g1b   = (const float*)d_in[7];
  const float* g2w   = (const float*)d_in[8];
  const float* g2b   = (const float*)d_in[9];
  float* out = (float*)d_out;

  char* ws = (char*)d_ws;
  short* x_bf    = (short*)(ws);               // 8 MiB
  short* w_qkv   = (short*)(ws + 8388608);     // 6 MiB
  short* w_proj  = (short*)(ws + 14680064);    // 2 MiB
  short* q_ws    = (short*)(ws + 16777216);    // 8 MiB (pre-scaled by 1/8)
  short* k_ws    = (short*)(ws + 25165824);    // 8 MiB (pre-scaled by gate*log2e)
  short* vt_ws   = (short*)(ws + 33554432);    // 8 MiB (transposed: b,h,d,n)
  short* attn_bf = (short*)(ws + 41943040);    // 8 MiB
  float* gate    = (float*)(ws + 50331648);    // 16 KiB

  cvt_gate_kernel<<<8208, 256, 0, stream>>>(x, qkvw, projw, mask, g1w, g1b, g2w, g2b,
                                            x_bf, w_qkv, w_proj, gate);

  dim3 gq(24, 32);
  gemm_qkv<<<gq, 256, 0, stream>>>(x_bf, w_qkv, qkvb, gate, q_ws, k_ws, vt_ws);

  attn_kernel<<<512, 256, 0, stream>>>(q_ws, k_ws, vt_ws, attn_bf);

  dim3 gp(8, 64);
  gemm_proj<<<gp, 256, 0, stream>>>(attn_bf, w_proj, projb, out);
}